// Round 8
// baseline (324.250 us; speedup 1.0000x reference)
//
#include <hip/hip_runtime.h>

#define DEV static __device__ __forceinline__

using f32x4 = __attribute__((ext_vector_type(4))) float;
using s16x8 = __attribute__((ext_vector_type(8))) short;   // 8 bf16 in 4 VGPRs

DEV unsigned short f2bf(float x) {          // fp32 -> bf16 bits, RNE
    unsigned int u = __float_as_uint(x);
    unsigned int r = (u + 0x7FFFu + ((u >> 16) & 1u)) >> 16;
    return (unsigned short)r;
}
DEV float bf2f(unsigned short u) {          // bf16 bits -> fp32 (exact)
    return __uint_as_float(((unsigned int)u) << 16);
}

DEV f32x4 mfma16(s16x8 a, s16x8 b, f32x4 c) {
    return __builtin_amdgcn_mfma_f32_16x16x32_bf16(a, b, c, 0, 0, 0);
}

DEV unsigned cvtpk_bf16(float a, float b) { // lo16 = bf16(a), hi16 = bf16(b)
    unsigned r;
    asm volatile("v_cvt_pk_bf16_f32 %0, %1, %2" : "=v"(r) : "v"(a), "v"(b));
    return r;
}

DEV void gload16(const unsigned short* g, short* l) {   // 16B global -> LDS direct
    __builtin_amdgcn_global_load_lds(
        (const __attribute__((address_space(1))) unsigned int*)g,
        (__attribute__((address_space(3))) unsigned int*)l, 16, 0, 0);
}

#define LOG2E 1.4426950408889634f

// ---------------------------------------------------------------------------
// split fp32 -> (hi, lo) bf16 planes
__global__ void k_split(const float* __restrict__ in, unsigned short* __restrict__ hi,
                        unsigned short* __restrict__ lo, int n4) {
    for (int i = blockIdx.x * blockDim.x + threadIdx.x; i < n4; i += gridDim.x * blockDim.x) {
        float4 v = ((const float4*)in)[i];
        ushort4 h, l;
        h.x = f2bf(v.x); l.x = f2bf(v.x - bf2f(h.x));
        h.y = f2bf(v.y); l.y = f2bf(v.y - bf2f(h.y));
        h.z = f2bf(v.z); l.z = f2bf(v.z - bf2f(h.z));
        h.w = f2bf(v.w); l.w = f2bf(v.w - bf2f(h.w));
        ((ushort4*)hi)[i] = h;
        ((ushort4*)lo)[i] = l;
    }
}

// ---------------------------------------------------------------------------
// Fused weight prep: blocks 0..255 transpose+split the four 512x512 weights
// (Wq scaled by qs) into [n][k] hi/lo planes; blocks 256..261 build
// bcat = [bq*qs | bk | bv].
__global__ void k_wfuse(const float* __restrict__ Wq, const float* __restrict__ Wk,
                        const float* __restrict__ Wv, const float* __restrict__ Wo,
                        const float* __restrict__ bq, const float* __restrict__ bk,
                        const float* __restrict__ bv,
                        unsigned short* __restrict__ WBhi, unsigned short* __restrict__ WBlo,
                        unsigned short* __restrict__ Wothi, unsigned short* __restrict__ Wotlo,
                        float* __restrict__ bcat, float qs) {
    __shared__ float tile[64][65];
    int blk = blockIdx.x;
    if (blk >= 256) {
        int i = (blk - 256) * 256 + threadIdx.x;
        bcat[i] = (i < 512) ? bq[i] * qs : (i < 1024) ? bk[i - 512] : bv[i - 1024];
        return;
    }
    int wi = blk >> 6, sub = blk & 63;
    const float* W = (wi == 0) ? Wq : (wi == 1) ? Wk : (wi == 2) ? Wv : Wo;
    float scale = (wi == 0) ? qs : 1.0f;
    unsigned short* Thi = (wi < 3) ? WBhi + (size_t)wi * 512 * 512 : Wothi;
    unsigned short* Tlo = (wi < 3) ? WBlo + (size_t)wi * 512 * 512 : Wotlo;
    int bk0 = (sub >> 3) * 64, bn = (sub & 7) * 64;
    int t = threadIdx.x;
    int r = t >> 2, c4 = (t & 3) * 16;
#pragma unroll
    for (int j = 0; j < 16; j += 4) {
        float4 v = *(const float4*)&W[(size_t)(bk0 + r) * 512 + bn + c4 + j];
        tile[r][c4 + j + 0] = v.x; tile[r][c4 + j + 1] = v.y;
        tile[r][c4 + j + 2] = v.z; tile[r][c4 + j + 3] = v.w;
    }
    __syncthreads();
    int n = t >> 2, k4 = (t & 3) * 16;
#pragma unroll
    for (int j = 0; j < 16; ++j) {
        float x = tile[k4 + j][n] * scale;
        unsigned short h = f2bf(x);
        Thi[(size_t)(bn + n) * 512 + bk0 + k4 + j] = h;
        Tlo[(size_t)(bn + n) * 512 + bk0 + k4 + j] = f2bf(x - bf2f(h));
    }
}

// ---------------------------------------------------------------------------
// GEMM, 128x128 tile, BK=64, stacked-K' = 3*512: A segs [hi,hi,lo] x B segs [hi,lo,hi].
// LDS XOR-swizzled via pre-swizzled global source (global_load_lds writes linearly).
// MODE 0 (N'=1536): sel0 -> Qhi only; sel1 -> Khi+Klo; sel2 -> V written DIRECTLY
//   TRANSPOSED (bf16-hi) to Vt[(b*8+h)*64+d][4096] (fuses old k_vt).
// MODE 1 (N=512): fp32 output + bias.
template <int MODE>
__global__ __launch_bounds__(256, 3) void k_gemm2(
    const unsigned short* __restrict__ Ahi, const unsigned short* __restrict__ Alo,
    const unsigned short* __restrict__ Bhi, const unsigned short* __restrict__ Blo,
    const float* __restrict__ bias,
    unsigned short* __restrict__ Qh,
    unsigned short* __restrict__ Kh, unsigned short* __restrict__ Kl,
    unsigned short* __restrict__ Vt,
    float* __restrict__ Cf) {
    __shared__ short As[128 * 64];
    __shared__ short Bs[128 * 64];
    int t = threadIdx.x, lane = t & 63, w = t >> 6;
    int wr = w >> 1, wc = w & 1, lr = lane & 15, lg = lane >> 4;
    int bm = blockIdx.y * 128, bn = blockIdx.x * 128;
    f32x4 acc[4][4] = {};
    int srow = t >> 3;                       // 0..31 (4 passes of 32 rows)
    int sc = t & 7;                          // 16B chunk in row
    int gcol = (sc ^ (srow & 7)) * 8;        // pre-swizzled source col (shorts)
    int axr = (lr & 7) * 8;                  // reader-side XOR operand (shorts)
    for (int c = 0; c < 24; ++c) {
        int seg = c >> 3, kb = (c & 7) * 64;
        const unsigned short* Ap = (seg < 2) ? Ahi : Alo;
        const unsigned short* Bp = (seg == 1) ? Blo : Bhi;
        const unsigned short* ag = Ap + (size_t)(bm + srow) * 512 + kb + gcol;
        const unsigned short* bg = Bp + (size_t)(bn + srow) * 512 + kb + gcol;
#pragma unroll
        for (int ps = 0; ps < 4; ++ps) {
            gload16(ag + (size_t)ps * 32 * 512, &As[(srow + ps * 32) * 64 + sc * 8]);
            gload16(bg + (size_t)ps * 32 * 512, &Bs[(srow + ps * 32) * 64 + sc * 8]);
        }
        __syncthreads();
#pragma unroll
        for (int kk = 0; kk < 2; ++kk) {
            s16x8 af[4], bf[4];
#pragma unroll
            for (int i = 0; i < 4; ++i)
                af[i] = *(const s16x8*)&As[(wr * 64 + i * 16 + lr) * 64 + ((kk * 32 + lg * 8) ^ axr)];
#pragma unroll
            for (int i = 0; i < 4; ++i)
                bf[i] = *(const s16x8*)&Bs[(wc * 64 + i * 16 + lr) * 64 + ((kk * 32 + lg * 8) ^ axr)];
#pragma unroll
            for (int i = 0; i < 4; ++i)
#pragma unroll
                for (int j = 0; j < 4; ++j) acc[i][j] = mfma16(af[i], bf[j], acc[i][j]);
        }
        __syncthreads();
    }
    int sel = bn >> 9;   // block-uniform (128-wide tiles never straddle a 512 segment)
#pragma unroll
    for (int i = 0; i < 4; ++i)
#pragma unroll
        for (int j = 0; j < 4; ++j) {
            int m = bm + wr * 64 + i * 16 + lg * 4;
            int n0 = bn + wc * 64 + j * 16;          // lr-independent base
            float bv = bias[n0 + lr];
            if (MODE == 1) {
#pragma unroll
                for (int r = 0; r < 4; ++r)
                    Cf[(size_t)(m + r) * 512 + n0 + lr] = acc[i][j][r] + bv;
            } else if (sel == 0) {                   // Q: hi plane only
                int col = (n0 & 511) + lr;
#pragma unroll
                for (int r = 0; r < 4; ++r)
                    Qh[(size_t)(m + r) * 512 + col] = f2bf(acc[i][j][r] + bv);
            } else if (sel == 1) {                   // K: hi + lo planes
                int col = (n0 & 511) + lr;
#pragma unroll
                for (int r = 0; r < 4; ++r) {
                    float v = acc[i][j][r] + bv;
                    unsigned short hh = f2bf(v);
                    Kh[(size_t)(m + r) * 512 + col] = hh;
                    Kl[(size_t)(m + r) * 512 + col] = f2bf(v - bf2f(hh));
                }
            } else {                                 // V: transposed bf16-hi
                int nc = (n0 & 511) + lr;            // h*64 + d
                int bidx = m >> 12, s = m & 4095;    // 4 consecutive s = r
                size_t row = ((size_t)bidx * 8 + (nc >> 6)) * 64 + (nc & 63);
                uint2 pv;
                pv.x = cvtpk_bf16(acc[i][j][0] + bv, acc[i][j][1] + bv);
                pv.y = cvtpk_bf16(acc[i][j][2] + bv, acc[i][j][3] + bv);
                *(uint2*)&Vt[row * 4096 + s] = pv;
            }
        }
}

// ---------------------------------------------------------------------------
// Flash attention, exp2-domain scores (log2e folded into Wq/bq upstream).
// Q bf16-hi only; K hi+lo planes; V bf16-hi transposed [bh*64+d][4096].
// Block: 8 waves x 16 q-rows = 128 q-rows; KBLK = 64; reg-prefetched staging.
// 512 threads, 44 KB LDS -> 2 blocks/CU = 4 waves/SIMD (occupancy lever vs R6).
// Scores: mfma(a=K, b=Q) -> S[k][q], lane&15 = q. PV: mfma(a=Vt, b=P) -> O[d][q].
// Per kt per wave: 16 QK MFMA + 8 PV MFMA + 16 exp2.
__global__ __launch_bounds__(512, 4) void k_attn(
    const unsigned short* __restrict__ Qhi,
    const unsigned short* __restrict__ Khi, const unsigned short* __restrict__ Klo,
    const unsigned short* __restrict__ Vthi,
    unsigned short* __restrict__ Ohi, unsigned short* __restrict__ Olo) {
    // single LDS pool: K [64][136] @0, V [64][72] @8704, P 8x[16][72] @13312
    __shared__ short L[22528];
    short* Kls = &L[0];
    short* Vls = &L[8704];
    int t = threadIdx.x, lane = t & 63, w = t >> 6;   // w = 0..7
    int lr = lane & 15, lg = lane >> 4;
    int qt = blockIdx.x & 31, bh = blockIdx.x >> 5;
    int b = bh >> 3, h = bh & 7;
    int qbase = qt * 128 + w * 16;
    short* pw = &L[13312 + w * 1152];    // per-wave P [16][72]

    s16x8 qr[2];                          // Q row q = qbase + lr, d-halves
    {
        size_t mrow = (size_t)(b * 4096 + qbase + lr) * 512 + h * 64;
        qr[0] = *(const s16x8*)&Qhi[mrow + lg * 8];
        qr[1] = *(const s16x8*)&Qhi[mrow + 32 + lg * 8];
    }

    f32x4 oacc[4] = {};
    float mrun = -1e30f, lrun = 0.f;

    // staging: K: thread t -> row = t>>3, 16-short chunk kp = t&7 of [hi|lo] 128-short row
    //          V: thread t -> row = t>>3, 8-short chunk (t&7)
    int krow = t >> 3, kp = t & 7;
    const unsigned short* Kb = ((kp & 4) ? Klo : Khi) +
        (size_t)(b * 4096 + krow) * 512 + h * 64 + (kp & 3) * 16;
    int vc = (t & 7) * 8;
    const unsigned short* Vb = Vthi + (size_t)(bh * 64 + krow) * 4096 + vc;

    s16x8 k0, k1, v0;
    k0 = *(const s16x8*)(Kb); k1 = *(const s16x8*)(Kb + 8);
    v0 = *(const s16x8*)(Vb);

    for (int kt = 0; kt < 64; ++kt) {
        *(s16x8*)&Kls[krow * 136 + kp * 16] = k0;
        *(s16x8*)&Kls[krow * 136 + kp * 16 + 8] = k1;
        *(s16x8*)&Vls[krow * 72 + vc] = v0;
        {   // prefetch next tile into regs (lands under compute)
            int ktn = (kt < 63) ? kt + 1 : 63;
            const unsigned short* kg = Kb + (size_t)ktn * 64 * 512;
            const unsigned short* vg = Vb + ktn * 64;
            k0 = *(const s16x8*)(kg); k1 = *(const s16x8*)(kg + 8);
            v0 = *(const s16x8*)(vg);
        }
        __syncthreads();

        // ---- scores: S[k][q] = (Khi + Klo) . Qhi ----
        f32x4 sacc[4] = {};
        __builtin_amdgcn_s_setprio(1);
#pragma unroll
        for (int kk = 0; kk < 4; ++kk) {            // kk: hi-d0, hi-d1, lo-d0, lo-d1
            int qa = kk & 1;
#pragma unroll
            for (int kf = 0; kf < 4; ++kf) {
                s16x8 af = *(const s16x8*)&Kls[(kf * 16 + lr) * 136 + kk * 32 + lg * 8];
                sacc[kf] = mfma16(af, qr[qa], sacc[kf]);
            }
        }
        __builtin_amdgcn_s_setprio(0);

        // ---- online softmax (exp2 domain, defer-max THR=4) + P pack ----
        {
            float tmax = -1e30f;
#pragma unroll
            for (int kf = 0; kf < 4; ++kf)
#pragma unroll
                for (int r = 0; r < 4; ++r) tmax = fmaxf(tmax, sacc[kf][r]);
            tmax = fmaxf(tmax, __shfl_xor(tmax, 16));
            tmax = fmaxf(tmax, __shfl_xor(tmax, 32));
            if (!__all(tmax <= mrun + 4.0f)) {       // rescale only when max grew
                float mnew = fmaxf(mrun, tmax);
                float alpha = exp2f(mrun - mnew);
                mrun = mnew;
                lrun *= alpha;
#pragma unroll
                for (int df = 0; df < 4; ++df) oacc[df] *= alpha;
            }
            float m = mrun;
            float tsum = 0.f;
#pragma unroll
            for (int kf = 0; kf < 4; ++kf)
#pragma unroll
                for (int r = 0; r < 4; ++r) {
                    float pv = exp2f(sacc[kf][r] - m);   // <= 2^4
                    sacc[kf][r] = pv;
                    tsum += pv;
                }
            tsum += __shfl_xor(tsum, 16);
            tsum += __shfl_xor(tsum, 32);
            lrun += tsum;
#pragma unroll
            for (int kf = 0; kf < 4; ++kf) {
                uint2 hv;
                hv.x = cvtpk_bf16(sacc[kf][0], sacc[kf][1]);
                hv.y = cvtpk_bf16(sacc[kf][2], sacc[kf][3]);
                *(uint2*)&pw[lr * 72 + kf * 16 + lg * 4] = hv;
            }
        }

        // ---- PV: O[d][q] += Vhi . P ----
        s16x8 pfr[2];
        pfr[0] = *(const s16x8*)&pw[lr * 72 + lg * 8];
        pfr[1] = *(const s16x8*)&pw[lr * 72 + 32 + lg * 8];
        __builtin_amdgcn_s_setprio(1);
#pragma unroll
        for (int vv = 0; vv < 2; ++vv) {
#pragma unroll
            for (int df = 0; df < 4; ++df) {
                s16x8 vf = *(const s16x8*)&Vls[(df * 16 + lr) * 72 + vv * 32 + lg * 8];
                oacc[df] = mfma16(vf, pfr[vv], oacc[df]);
            }
        }
        __builtin_amdgcn_s_setprio(0);
        __syncthreads();
    }

    // epilogue: normalize, transpose O via per-wave LDS region ([16][68] f32,
    // 4352 B each at w*4352 — all compute reads done after final barrier),
    // write hi/lo planes
    float inv = 1.f / lrun;
    float* ow = (float*)&L[0] + w * 1088;
#pragma unroll
    for (int df = 0; df < 4; ++df) {
        f32x4 v = oacc[df] * inv;
        *(f32x4*)&ow[lr * 68 + df * 16 + lg * 4] = v;
    }
    {
        int q = lane >> 2;                 // 0..15
        int dc = (lane & 3) * 16;
        size_t gbase = (size_t)(b * 4096 + qbase + q) * 512 + h * 64 + dc;
        s16x8 hv0, hv1, lv0, lv1;
#pragma unroll
        for (int j = 0; j < 8; ++j) {
            float x = ow[q * 68 + dc + j];
            unsigned short hh = f2bf(x);
            hv0[j] = (short)hh; lv0[j] = (short)f2bf(x - bf2f(hh));
        }
#pragma unroll
        for (int j = 0; j < 8; ++j) {
            float x = ow[q * 68 + dc + 8 + j];
            unsigned short hh = f2bf(x);
            hv1[j] = (short)hh; lv1[j] = (short)f2bf(x - bf2f(hh));
        }
        *(s16x8*)&Ohi[gbase] = hv0;     *(s16x8*)&Ohi[gbase + 8] = hv1;
        *(s16x8*)&Olo[gbase] = lv0;     *(s16x8*)&Olo[gbase + 8] = lv1;
    }
}

// ---------------------------------------------------------------------------
extern "C" void kernel_launch(void* const* d_in, const int* in_sizes, int n_in,
                              void* d_out, int out_size, void* d_ws, size_t ws_size,
                              hipStream_t stream) {
    const float* x  = (const float*)d_in[0];
    const float* Wq = (const float*)d_in[1];
    const float* bq = (const float*)d_in[2];
    const float* Wk = (const float*)d_in[3];
    const float* bk = (const float*)d_in[4];
    const float* Wv = (const float*)d_in[5];
    const float* bv = (const float*)d_in[6];
    const float* Wo = (const float*)d_in[7];
    const float* bo = (const float*)d_in[8];
    float* out = (float*)d_out;

    char* ws = (char*)d_ws;
    const size_t PLANE = (size_t)8192 * 512 * 2;   // 8 MB (bf16 plane)
    const size_t WBPL  = (size_t)1536 * 512 * 2;   // 1.5 MB (fused W planes)
    const size_t WPL   = (size_t)512 * 512 * 2;    // 512 KB
    size_t off = 0;
    unsigned short* Xhi   = (unsigned short*)(ws + off); off += PLANE;
    unsigned short* Xlo   = (unsigned short*)(ws + off); off += PLANE;
    unsigned short* WBhi  = (unsigned short*)(ws + off); off += WBPL;
    unsigned short* WBlo  = (unsigned short*)(ws + off); off += WBPL;
    unsigned short* Wothi = (unsigned short*)(ws + off); off += WPL;
    unsigned short* Wotlo = (unsigned short*)(ws + off); off += WPL;
    float*          bcat  = (float*)(ws + off);          off += 1536 * 4;
    unsigned short* Qhi   = (unsigned short*)(ws + off); off += PLANE;
    unsigned short* Khi   = (unsigned short*)(ws + off); off += PLANE;
    unsigned short* Klo   = (unsigned short*)(ws + off); off += PLANE;
    unsigned short* Vthi  = (unsigned short*)(ws + off); off += PLANE;
    unsigned short* Ohi = Xhi;   // X is dead after the QKV GEMM
    unsigned short* Olo = Xlo;

    const float QS = 0.125f * LOG2E;   // 1/sqrt(64) * log2(e): exp2-domain scores

    k_split<<<1024, 256, 0, stream>>>(x, Xhi, Xlo, 8192 * 512 / 4);
    k_wfuse<<<262, 256, 0, stream>>>(Wq, Wk, Wv, Wo, bq, bk, bv,
                                     WBhi, WBlo, Wothi, Wotlo, bcat, QS);
    k_gemm2<0><<<dim3(12, 64), 256, 0, stream>>>(Xhi, Xlo, WBhi, WBlo, bcat,
                                                 Qhi, Khi, Klo, Vthi, nullptr);
    k_attn<<<512, 512, 0, stream>>>(Qhi, Khi, Klo, Vthi, Ohi, Olo);
    k_gemm2<1><<<dim3(4, 64), 256, 0, stream>>>(Ohi, Olo, Wothi, Wotlo, bo,
                                                nullptr, nullptr, nullptr, nullptr, out);
}

// Round 9
// 312.325 us; speedup vs baseline: 1.0382x; 1.0382x over previous
//
#include <hip/hip_runtime.h>

#define DEV static __device__ __forceinline__

using f32x4 = __attribute__((ext_vector_type(4))) float;
using s16x8 = __attribute__((ext_vector_type(8))) short;   // 8 bf16 in 4 VGPRs

DEV unsigned short f2bf(float x) {          // fp32 -> bf16 bits, RNE
    unsigned int u = __float_as_uint(x);
    unsigned int r = (u + 0x7FFFu + ((u >> 16) & 1u)) >> 16;
    return (unsigned short)r;
}
DEV float bf2f(unsigned short u) {          // bf16 bits -> fp32 (exact)
    return __uint_as_float(((unsigned int)u) << 16);
}

DEV f32x4 mfma16(s16x8 a, s16x8 b, f32x4 c) {
    return __builtin_amdgcn_mfma_f32_16x16x32_bf16(a, b, c, 0, 0, 0);
}

DEV unsigned cvtpk_bf16(float a, float b) { // lo16 = bf16(a), hi16 = bf16(b)
    unsigned r;
    asm volatile("v_cvt_pk_bf16_f32 %0, %1, %2" : "=v"(r) : "v"(a), "v"(b));
    return r;
}

DEV void gload16(const unsigned short* g, short* l) {   // 16B global -> LDS direct
    __builtin_amdgcn_global_load_lds(
        (const __attribute__((address_space(1))) unsigned int*)g,
        (__attribute__((address_space(3))) unsigned int*)l, 16, 0, 0);
}

#define LOG2E 1.4426950408889634f

// ---------------------------------------------------------------------------
// split fp32 -> (hi, lo) bf16 planes
__global__ void k_split(const float* __restrict__ in, unsigned short* __restrict__ hi,
                        unsigned short* __restrict__ lo, int n4) {
    for (int i = blockIdx.x * blockDim.x + threadIdx.x; i < n4; i += gridDim.x * blockDim.x) {
        float4 v = ((const float4*)in)[i];
        ushort4 h, l;
        h.x = f2bf(v.x); l.x = f2bf(v.x - bf2f(h.x));
        h.y = f2bf(v.y); l.y = f2bf(v.y - bf2f(h.y));
        h.z = f2bf(v.z); l.z = f2bf(v.z - bf2f(h.z));
        h.w = f2bf(v.w); l.w = f2bf(v.w - bf2f(h.w));
        ((ushort4*)hi)[i] = h;
        ((ushort4*)lo)[i] = l;
    }
}

// ---------------------------------------------------------------------------
// Fused weight prep: blocks 0..255 transpose+split the four 512x512 weights
// (Wq scaled by qs) into [n][k] hi/lo planes; blocks 256..261 build
// bcat = [bq*qs | bk | bv].
__global__ void k_wfuse(const float* __restrict__ Wq, const float* __restrict__ Wk,
                        const float* __restrict__ Wv, const float* __restrict__ Wo,
                        const float* __restrict__ bq, const float* __restrict__ bk,
                        const float* __restrict__ bv,
                        unsigned short* __restrict__ WBhi, unsigned short* __restrict__ WBlo,
                        unsigned short* __restrict__ Wothi, unsigned short* __restrict__ Wotlo,
                        float* __restrict__ bcat, float qs) {
    __shared__ float tile[64][65];
    int blk = blockIdx.x;
    if (blk >= 256) {
        int i = (blk - 256) * 256 + threadIdx.x;
        bcat[i] = (i < 512) ? bq[i] * qs : (i < 1024) ? bk[i - 512] : bv[i - 1024];
        return;
    }
    int wi = blk >> 6, sub = blk & 63;
    const float* W = (wi == 0) ? Wq : (wi == 1) ? Wk : (wi == 2) ? Wv : Wo;
    float scale = (wi == 0) ? qs : 1.0f;
    unsigned short* Thi = (wi < 3) ? WBhi + (size_t)wi * 512 * 512 : Wothi;
    unsigned short* Tlo = (wi < 3) ? WBlo + (size_t)wi * 512 * 512 : Wotlo;
    int bk0 = (sub >> 3) * 64, bn = (sub & 7) * 64;
    int t = threadIdx.x;
    int r = t >> 2, c4 = (t & 3) * 16;
#pragma unroll
    for (int j = 0; j < 16; j += 4) {
        float4 v = *(const float4*)&W[(size_t)(bk0 + r) * 512 + bn + c4 + j];
        tile[r][c4 + j + 0] = v.x; tile[r][c4 + j + 1] = v.y;
        tile[r][c4 + j + 2] = v.z; tile[r][c4 + j + 3] = v.w;
    }
    __syncthreads();
    int n = t >> 2, k4 = (t & 3) * 16;
#pragma unroll
    for (int j = 0; j < 16; ++j) {
        float x = tile[k4 + j][n] * scale;
        unsigned short h = f2bf(x);
        Thi[(size_t)(bn + n) * 512 + bk0 + k4 + j] = h;
        Tlo[(size_t)(bn + n) * 512 + bk0 + k4 + j] = f2bf(x - bf2f(h));
    }
}

// ---------------------------------------------------------------------------
// GEMM, 128x128 tile, BK=64. LDS XOR-swizzled via pre-swizzled global source.
// MODE 0 (N'=1536, K'=3*512: A[hi,hi,lo] x B[hi,lo,hi]):
//   sel0 -> Qhi; sel1 -> Khi (hi only); sel2 -> V transposed bf16-hi to Vt.
// MODE 1 (N=512, K'=2*512: A[hi,hi] x B[hi,lo]): fp32 output + bias.
template <int MODE>
__global__ __launch_bounds__(256, 3) void k_gemm2(
    const unsigned short* __restrict__ Ahi, const unsigned short* __restrict__ Alo,
    const unsigned short* __restrict__ Bhi, const unsigned short* __restrict__ Blo,
    const float* __restrict__ bias,
    unsigned short* __restrict__ Qh,
    unsigned short* __restrict__ Kh,
    unsigned short* __restrict__ Vt,
    float* __restrict__ Cf) {
    __shared__ short As[128 * 64];
    __shared__ short Bs[128 * 64];
    int t = threadIdx.x, lane = t & 63, w = t >> 6;
    int wr = w >> 1, wc = w & 1, lr = lane & 15, lg = lane >> 4;
    int bm = blockIdx.y * 128, bn = blockIdx.x * 128;
    f32x4 acc[4][4] = {};
    int srow = t >> 3;                       // 0..31 (4 passes of 32 rows)
    int sc = t & 7;                          // 16B chunk in row
    int gcol = (sc ^ (srow & 7)) * 8;        // pre-swizzled source col (shorts)
    int axr = (lr & 7) * 8;                  // reader-side XOR operand (shorts)
    const int NC = (MODE == 0) ? 24 : 16;
    for (int c = 0; c < NC; ++c) {
        int seg = c >> 3, kb = (c & 7) * 64;
        const unsigned short* Ap, * Bp;
        if (MODE == 0) {
            Ap = (seg < 2) ? Ahi : Alo;
            Bp = (seg == 1) ? Blo : Bhi;
        } else {
            Ap = Ahi;
            Bp = seg ? Blo : Bhi;
        }
        const unsigned short* ag = Ap + (size_t)(bm + srow) * 512 + kb + gcol;
        const unsigned short* bg = Bp + (size_t)(bn + srow) * 512 + kb + gcol;
#pragma unroll
        for (int ps = 0; ps < 4; ++ps) {
            gload16(ag + (size_t)ps * 32 * 512, &As[(srow + ps * 32) * 64 + sc * 8]);
            gload16(bg + (size_t)ps * 32 * 512, &Bs[(srow + ps * 32) * 64 + sc * 8]);
        }
        __syncthreads();
#pragma unroll
        for (int kk = 0; kk < 2; ++kk) {
            s16x8 af[4], bf[4];
#pragma unroll
            for (int i = 0; i < 4; ++i)
                af[i] = *(const s16x8*)&As[(wr * 64 + i * 16 + lr) * 64 + ((kk * 32 + lg * 8) ^ axr)];
#pragma unroll
            for (int i = 0; i < 4; ++i)
                bf[i] = *(const s16x8*)&Bs[(wc * 64 + i * 16 + lr) * 64 + ((kk * 32 + lg * 8) ^ axr)];
#pragma unroll
            for (int i = 0; i < 4; ++i)
#pragma unroll
                for (int j = 0; j < 4; ++j) acc[i][j] = mfma16(af[i], bf[j], acc[i][j]);
        }
        __syncthreads();
    }
    int sel = bn >> 9;   // block-uniform (128-wide tiles never straddle a 512 segment)
#pragma unroll
    for (int i = 0; i < 4; ++i)
#pragma unroll
        for (int j = 0; j < 4; ++j) {
            int m = bm + wr * 64 + i * 16 + lg * 4;
            int n0 = bn + wc * 64 + j * 16;          // lr-independent base
            float bv = bias[n0 + lr];
            if (MODE == 1) {
#pragma unroll
                for (int r = 0; r < 4; ++r)
                    Cf[(size_t)(m + r) * 512 + n0 + lr] = acc[i][j][r] + bv;
            } else if (sel < 2) {                    // Q or K: hi plane only
                int col = (n0 & 511) + lr;
                unsigned short* Ph = sel ? Kh : Qh;
#pragma unroll
                for (int r = 0; r < 4; ++r)
                    Ph[(size_t)(m + r) * 512 + col] = f2bf(acc[i][j][r] + bv);
            } else {                                 // V: transposed bf16-hi
                int nc = (n0 & 511) + lr;            // h*64 + d
                int bidx = m >> 12, s = m & 4095;    // 4 consecutive s = r
                size_t row = ((size_t)bidx * 8 + (nc >> 6)) * 64 + (nc & 63);
                uint2 pv;
                pv.x = cvtpk_bf16(acc[i][j][0] + bv, acc[i][j][1] + bv);
                pv.y = cvtpk_bf16(acc[i][j][2] + bv, acc[i][j][3] + bv);
                *(uint2*)&Vt[row * 4096 + s] = pv;
            }
        }
}

// ---------------------------------------------------------------------------
// Flash attention, exp2-domain scores (log2e folded into Wq/bq upstream).
// Q,K bf16-hi [B*S][512]; V bf16-hi transposed [bh*64+d][4096]. O: hi only.
// Block: 8 waves x 32 q-rows = 256 q-rows; grid 256 (XCD-swizzled); KBLK=64.
// R8 lesson: kernel is LDS-read bound (each wave reads the full K/V tile).
// 32 q/wave amortizes K/V reads over 2x q vs R8; K-lo dropped (halves K reads
// + QK MFMA). Per kt per wave: 16 QK MFMA + 16 PV MFMA, 32 exp2.
__global__ __launch_bounds__(512, 2) void k_attn(
    const unsigned short* __restrict__ Qhi,
    const unsigned short* __restrict__ Khi,
    const unsigned short* __restrict__ Vthi,
    unsigned short* __restrict__ Ohi) {
    // LDS pool (shorts): K [64][72] @0, V [64][72] @4608, P 8x[32][72] @9216
    __shared__ short L[27648];
    short* Kls = &L[0];
    short* Vls = &L[4608];
    int t = threadIdx.x, lane = t & 63, w = t >> 6;   // w = 0..7
    int lr = lane & 15, lg = lane >> 4;
    int bid = blockIdx.x;
    int swz = (bid & 7) * 32 + (bid >> 3);            // bijective XCD swizzle (256%8==0)
    int bh = swz >> 4, qt = swz & 15;
    int b = bh >> 3, h = bh & 7;
    int qbase = qt * 256 + w * 32;
    short* pw = &L[9216 + w * 2304];                  // per-wave P [32][72]

    s16x8 qr[2][2];                       // [qf][d-half]
#pragma unroll
    for (int qf = 0; qf < 2; ++qf) {
        size_t mrow = (size_t)(b * 4096 + qbase + qf * 16 + lr) * 512 + h * 64;
        qr[qf][0] = *(const s16x8*)&Qhi[mrow + lg * 8];
        qr[qf][1] = *(const s16x8*)&Qhi[mrow + 32 + lg * 8];
    }

    f32x4 oacc[4][2] = {};
    float mrun[2] = {-1e30f, -1e30f}, lrun[2] = {0.f, 0.f};

    // staging: thread t -> K row t>>3 (0..63), 16B chunk (t&7); same for V.
    int krow = t >> 3, kc = (t & 7) * 8;
    const unsigned short* Kb = Khi + (size_t)(b * 4096 + krow) * 512 + h * 64 + kc;
    const unsigned short* Vb = Vthi + (size_t)(bh * 64 + krow) * 4096 + kc;
    s16x8 k0 = *(const s16x8*)Kb;
    s16x8 v0 = *(const s16x8*)Vb;

    for (int kt = 0; kt < 64; ++kt) {
        *(s16x8*)&Kls[krow * 72 + kc] = k0;
        *(s16x8*)&Vls[krow * 72 + kc] = v0;
        {   // prefetch next tile into regs (lands under compute)
            int ktn = (kt < 63) ? kt + 1 : 63;
            k0 = *(const s16x8*)(Kb + (size_t)ktn * 64 * 512);
            v0 = *(const s16x8*)(Vb + ktn * 64);
        }
        __syncthreads();

        // ---- scores: S[k][q] = Khi . Qhi ----
        f32x4 sacc[4][2] = {};
        __builtin_amdgcn_s_setprio(1);
#pragma unroll
        for (int kk = 0; kk < 2; ++kk)                // d-halves
#pragma unroll
            for (int kf = 0; kf < 4; ++kf) {
                s16x8 af = *(const s16x8*)&Kls[(kf * 16 + lr) * 72 + kk * 32 + lg * 8];
                sacc[kf][0] = mfma16(af, qr[0][kk], sacc[kf][0]);
                sacc[kf][1] = mfma16(af, qr[1][kk], sacc[kf][1]);
            }
        __builtin_amdgcn_s_setprio(0);

        // ---- online softmax (exp2 domain, defer-max THR=4) + P pack ----
#pragma unroll
        for (int qf = 0; qf < 2; ++qf) {
            float tmax = -1e30f;
#pragma unroll
            for (int kf = 0; kf < 4; ++kf)
#pragma unroll
                for (int r = 0; r < 4; ++r) tmax = fmaxf(tmax, sacc[kf][qf][r]);
            tmax = fmaxf(tmax, __shfl_xor(tmax, 16));
            tmax = fmaxf(tmax, __shfl_xor(tmax, 32));
            if (!__all(tmax <= mrun[qf] + 4.0f)) {    // rescale only when max grew
                float mnew = fmaxf(mrun[qf], tmax);
                float alpha = exp2f(mrun[qf] - mnew);
                mrun[qf] = mnew;
                lrun[qf] *= alpha;
#pragma unroll
                for (int df = 0; df < 4; ++df) oacc[df][qf] *= alpha;
            }
            float m = mrun[qf];
            float tsum = 0.f;
#pragma unroll
            for (int kf = 0; kf < 4; ++kf)
#pragma unroll
                for (int r = 0; r < 4; ++r) {
                    float pv = exp2f(sacc[kf][qf][r] - m);   // <= 2^4
                    sacc[kf][qf][r] = pv;
                    tsum += pv;
                }
            tsum += __shfl_xor(tsum, 16);
            tsum += __shfl_xor(tsum, 32);
            lrun[qf] += tsum;

            int q = qf * 16 + lr;
#pragma unroll
            for (int kf = 0; kf < 4; ++kf) {
                uint2 hv;
                hv.x = cvtpk_bf16(sacc[kf][qf][0], sacc[kf][qf][1]);
                hv.y = cvtpk_bf16(sacc[kf][qf][2], sacc[kf][qf][3]);
                *(uint2*)&pw[q * 72 + kf * 16 + lg * 4] = hv;
            }
        }

        // ---- PV: O[d][q] += Vhi . P ----
        s16x8 pfr[2][2];
#pragma unroll
        for (int qf = 0; qf < 2; ++qf)
#pragma unroll
            for (int vv = 0; vv < 2; ++vv)
                pfr[qf][vv] = *(const s16x8*)&pw[(qf * 16 + lr) * 72 + vv * 32 + lg * 8];
        __builtin_amdgcn_s_setprio(1);
#pragma unroll
        for (int vv = 0; vv < 2; ++vv)
#pragma unroll
            for (int df = 0; df < 4; ++df) {
                s16x8 vf = *(const s16x8*)&Vls[(df * 16 + lr) * 72 + vv * 32 + lg * 8];
                oacc[df][0] = mfma16(vf, pfr[0][vv], oacc[df][0]);
                oacc[df][1] = mfma16(vf, pfr[1][vv], oacc[df][1]);
            }
        __builtin_amdgcn_s_setprio(0);
        __syncthreads();
    }

    // epilogue: normalize, transpose O via per-wave LDS region [16][68] f32
    // (two passes, one per qf); write Ohi only.
    float inv[2] = {1.f / lrun[0], 1.f / lrun[1]};
    float* ow = (float*)&L[0] + w * 1088;
#pragma unroll
    for (int pp = 0; pp < 2; ++pp) {
        if (pp) __syncthreads();
#pragma unroll
        for (int df = 0; df < 4; ++df) {
            f32x4 v = oacc[df][pp] * inv[pp];
            *(f32x4*)&ow[lr * 68 + df * 16 + lg * 4] = v;
        }
        int q = lane >> 2, dc = (lane & 3) * 16;
        f32x4 x0 = *(f32x4*)&ow[q * 68 + dc];
        f32x4 x1 = *(f32x4*)&ow[q * 68 + dc + 4];
        f32x4 x2 = *(f32x4*)&ow[q * 68 + dc + 8];
        f32x4 x3 = *(f32x4*)&ow[q * 68 + dc + 12];
        uint4 h0, h1;
        h0.x = cvtpk_bf16(x0[0], x0[1]); h0.y = cvtpk_bf16(x0[2], x0[3]);
        h0.z = cvtpk_bf16(x1[0], x1[1]); h0.w = cvtpk_bf16(x1[2], x1[3]);
        h1.x = cvtpk_bf16(x2[0], x2[1]); h1.y = cvtpk_bf16(x2[2], x2[3]);
        h1.z = cvtpk_bf16(x3[0], x3[1]); h1.w = cvtpk_bf16(x3[2], x3[3]);
        size_t gbase = (size_t)(b * 4096 + qbase + pp * 16 + q) * 512 + h * 64 + dc;
        *(uint4*)&Ohi[gbase] = h0;
        *(uint4*)&Ohi[gbase + 8] = h1;
    }
}

// ---------------------------------------------------------------------------
extern "C" void kernel_launch(void* const* d_in, const int* in_sizes, int n_in,
                              void* d_out, int out_size, void* d_ws, size_t ws_size,
                              hipStream_t stream) {
    const float* x  = (const float*)d_in[0];
    const float* Wq = (const float*)d_in[1];
    const float* bq = (const float*)d_in[2];
    const float* Wk = (const float*)d_in[3];
    const float* bk = (const float*)d_in[4];
    const float* Wv = (const float*)d_in[5];
    const float* bv = (const float*)d_in[6];
    const float* Wo = (const float*)d_in[7];
    const float* bo = (const float*)d_in[8];
    float* out = (float*)d_out;

    char* ws = (char*)d_ws;
    const size_t PLANE = (size_t)8192 * 512 * 2;   // 8 MB (bf16 plane)
    const size_t WBPL  = (size_t)1536 * 512 * 2;   // 1.5 MB (fused W planes)
    const size_t WPL   = (size_t)512 * 512 * 2;    // 512 KB
    size_t off = 0;
    unsigned short* Xhi   = (unsigned short*)(ws + off); off += PLANE;
    unsigned short* Xlo   = (unsigned short*)(ws + off); off += PLANE;
    unsigned short* WBhi  = (unsigned short*)(ws + off); off += WBPL;
    unsigned short* WBlo  = (unsigned short*)(ws + off); off += WBPL;
    unsigned short* Wothi = (unsigned short*)(ws + off); off += WPL;
    unsigned short* Wotlo = (unsigned short*)(ws + off); off += WPL;
    float*          bcat  = (float*)(ws + off);          off += 1536 * 4;
    unsigned short* Qhi   = (unsigned short*)(ws + off); off += PLANE;
    unsigned short* Khi   = (unsigned short*)(ws + off); off += PLANE;
    unsigned short* Vthi  = (unsigned short*)(ws + off); off += PLANE;
    unsigned short* Ohi = Xhi;   // X is dead after the QKV GEMM

    const float QS = 0.125f * LOG2E;   // 1/sqrt(64) * log2(e): exp2-domain scores

    k_split<<<1024, 256, 0, stream>>>(x, Xhi, Xlo, 8192 * 512 / 4);
    k_wfuse<<<262, 256, 0, stream>>>(Wq, Wk, Wv, Wo, bq, bk, bv,
                                     WBhi, WBlo, Wothi, Wotlo, bcat, QS);
    k_gemm2<0><<<dim3(12, 64), 256, 0, stream>>>(Xhi, Xlo, WBhi, WBlo, bcat,
                                                 Qhi, Khi, Vthi, nullptr);
    k_attn<<<256, 512, 0, stream>>>(Qhi, Khi, Vthi, Ohi);
    k_gemm2<1><<<dim3(4, 64), 256, 0, stream>>>(Ohi, nullptr, Wothi, Wotlo, bo,
                                                nullptr, nullptr, nullptr, out);
}